// Round 7
// baseline (836.991 us; speedup 1.0000x reference)
//
#include <hip/hip_runtime.h>
#include <math.h>

#define FIN 128
#define HDIM 64

// CSR-build (counting sort) geometry. Assumes N <= 131072 (src fits 17 bits,
// coarse buckets <= 256), Etot <= 2.09M (nblk <= 256). Instance: N=100k, E=1.6M.
#define EB 8192            // edges per block in p1/p2
#define B2SHIFT 9
#define B2 (1 << B2SHIFT)  // 512 dst per coarse bucket
#define SRCBITS 17
#define SRCMASK ((1u << SRCBITS) - 1u)
#define DBINS 256          // degree bins for the prop scheduling sort

typedef __attribute__((ext_vector_type(8))) short short8_t;  // 8 bf16 (4 VGPRs)
typedef __attribute__((ext_vector_type(4))) float f32x4;
typedef _Float16 h2_t __attribute__((ext_vector_type(2)));

__device__ __forceinline__ float2 h2f2(unsigned u) {
    h2_t h = __builtin_bit_cast(h2_t, u);
    return make_float2((float)h.x, (float)h.y);
}
__device__ __forceinline__ unsigned f2h2(float a, float b) {
    h2_t h; h.x = (_Float16)a; h.y = (_Float16)b;
    return __builtin_bit_cast(unsigned, h);
}
__device__ __forceinline__ unsigned short f2h1(float a) {
    _Float16 h = (_Float16)a;
    return __builtin_bit_cast(unsigned short, h);
}

__device__ __forceinline__ void split_bf16(float f, unsigned short& hi, unsigned short& lo) {
    unsigned b = __builtin_bit_cast(unsigned, f);
    hi = (unsigned short)(b >> 16);
    float fh = __builtin_bit_cast(float, b & 0xFFFF0000u);
    float fl = f - fh;
    lo = (unsigned short)(__builtin_bit_cast(unsigned, fl) >> 16);
}

// 8-wide dot of packed fp16 against f32-promoted: compiler emits v_fma_mix_f32.
__device__ __forceinline__ float dot8(uint4 v, const float* hd) {
    float2 a = h2f2(v.x), b = h2f2(v.y), c = h2f2(v.z), d = h2f2(v.w);
    float p = a.x * hd[0];
    p = fmaf(a.y, hd[1], p);
    p = fmaf(b.x, hd[2], p);
    p = fmaf(b.y, hd[3], p);
    p = fmaf(c.x, hd[4], p);
    p = fmaf(c.y, hd[5], p);
    p = fmaf(d.x, hd[6], p);
    p = fmaf(d.y, hd[7], p);
    return p;
}
__device__ __forceinline__ void acc8(float w, uint4 v, float* a) {
    float2 f0 = h2f2(v.x), f1 = h2f2(v.y), f2 = h2f2(v.z), f3 = h2f2(v.w);
    a[0] = fmaf(w, f0.x, a[0]); a[1] = fmaf(w, f0.y, a[1]);
    a[2] = fmaf(w, f1.x, a[2]); a[3] = fmaf(w, f1.y, a[3]);
    a[4] = fmaf(w, f2.x, a[4]); a[5] = fmaf(w, f2.y, a[5]);
    a[6] = fmaf(w, f3.x, a[6]); a[7] = fmaf(w, f3.y, a[7]);
}

// ---------------- CSR build: deterministic two-level counting sort ----------------

__global__ __launch_bounds__(256) void p1_hist(
    const int* __restrict__ ei, int* __restrict__ ph,
    int E, int Etot, int NB, int nblk)
{
    __shared__ int h[256];
    h[threadIdx.x] = 0;
    __syncthreads();
    const int base = blockIdx.x * EB;
    const int end = min(base + EB, Etot);
    for (int e = base + (int)threadIdx.x; e < end; e += 256) {
        int d = (e < E) ? ei[E + e] : (e - E);
        atomicAdd(&h[d >> B2SHIFT], 1);
    }
    __syncthreads();
    if ((int)threadIdx.x < NB) ph[threadIdx.x * nblk + blockIdx.x] = h[threadIdx.x];
}

// One block per bucket: exclusive scan of ph[b][0..nblk) in place, total -> btot[b]
__global__ __launch_bounds__(256) void p1_scanA(
    int* __restrict__ ph, int* __restrict__ btot, int nblk)
{
    __shared__ int wpart[4];
    const int b = blockIdx.x;
    const int t = threadIdx.x, lane = t & 63, w = t >> 6;
    int v = (t < nblk) ? ph[b * nblk + t] : 0;
    int s = v;
#pragma unroll
    for (int off = 1; off < 64; off <<= 1) {
        int u = __shfl_up(s, off, 64);
        if (lane >= off) s += u;
    }
    if (lane == 63) wpart[w] = s;
    __syncthreads();
    int wex = 0;
#pragma unroll
    for (int i = 0; i < 3; ++i) if (i < w) wex += wpart[i];
    if (t < nblk) ph[b * nblk + t] = wex + s - v;
    if (t == 255) btot[b] = wex + s;
}

// Single tiny block: scan bucket totals -> bbase[NB+1]; offsets[N] = Etot.
__global__ __launch_bounds__(256) void p1_scanB(
    const int* __restrict__ btot, int* __restrict__ bbase,
    int* __restrict__ offsets, int NB, int N)
{
    __shared__ int wpart[4];
    const int t = threadIdx.x, lane = t & 63, w = t >> 6;
    int v = (t < NB) ? btot[t] : 0;
    int s = v;
#pragma unroll
    for (int off = 1; off < 64; off <<= 1) {
        int u = __shfl_up(s, off, 64);
        if (lane >= off) s += u;
    }
    if (lane == 63) wpart[w] = s;
    __syncthreads();
    int wex = 0;
#pragma unroll
    for (int i = 0; i < 3; ++i) if (i < w) wex += wpart[i];
    if (t < NB) bbase[t] = wex + s - v;
    if (t == 255) { bbase[NB] = wex + s; offsets[N] = wex + s; }
}

__global__ __launch_bounds__(256) void p2_scatter(
    const int* __restrict__ ei, const int* __restrict__ ph,
    const int* __restrict__ bbase, unsigned* __restrict__ pairs,
    int E, int Etot, int NB, int nblk)
{
    __shared__ int cur[256];
    if ((int)threadIdx.x < NB)
        cur[threadIdx.x] = bbase[threadIdx.x] + ph[threadIdx.x * nblk + blockIdx.x];
    __syncthreads();
    const int base = blockIdx.x * EB;
    const int end = min(base + EB, Etot);
    for (int e = base + (int)threadIdx.x; e < end; e += 256) {
        int s, d;
        if (e < E) { s = ei[e]; d = ei[E + e]; }
        else       { s = e - E; d = s; }
        int pos = atomicAdd(&cur[d >> B2SHIFT], 1);
        pairs[pos] = ((unsigned)(d & (B2 - 1)) << SRCBITS) | (unsigned)s;
    }
}

// One block (256 thr) per bucket: 512-bin LDS hist + scan -> offsets, then scatter.
// Also feeds the global degree histogram for the prop scheduling sort.
__global__ __launch_bounds__(256) void p3_csr(
    const unsigned* __restrict__ pairs, const int* __restrict__ bbase,
    int* __restrict__ offsets, int* __restrict__ csr,
    int* __restrict__ dhist, int N)
{
    __shared__ int hist[B2];
    __shared__ int wp[4];
    const int b = blockIdx.x;
    const int p0 = bbase[b], p1 = bbase[b + 1];
    const int dbase = b << B2SHIFT;
    const int lane = threadIdx.x & 63, w = threadIdx.x >> 6;
    hist[threadIdx.x] = 0; hist[threadIdx.x + 256] = 0;
    __syncthreads();
    for (int i = p0 + (int)threadIdx.x; i < p1; i += 256)
        atomicAdd(&hist[pairs[i] >> SRCBITS], 1);
    __syncthreads();
    const int v0 = hist[2 * threadIdx.x], v1 = hist[2 * threadIdx.x + 1];
    const int t = v0 + v1;
    int s = t;
#pragma unroll
    for (int off = 1; off < 64; off <<= 1) {
        int u = __shfl_up(s, off, 64);
        if (lane >= off) s += u;
    }
    if (lane == 63) wp[w] = s;
    __syncthreads();
    int wex = 0;
#pragma unroll
    for (int i = 0; i < 3; ++i) if (i < w) wex += wp[i];
    const int tex = wex + (s - t);
    const int e0 = tex, e1 = tex + v0;
    const int d0 = dbase + 2 * (int)threadIdx.x, d1 = d0 + 1;
    if (d0 < N) { offsets[d0] = p0 + e0; atomicAdd(&dhist[min(v0, DBINS - 1)], 1); }
    if (d1 < N) { offsets[d1] = p0 + e1; atomicAdd(&dhist[min(v1, DBINS - 1)], 1); }
    __syncthreads();
    hist[2 * threadIdx.x] = e0; hist[2 * threadIdx.x + 1] = e1;
    __syncthreads();
    for (int i = p0 + (int)threadIdx.x; i < p1; i += 256) {
        unsigned pk = pairs[i];
        int pos = p0 + atomicAdd(&hist[pk >> SRCBITS], 1);
        csr[pos] = (int)(pk & SRCMASK);
    }
}

// Tiny: exclusive scan of dhist[256] -> dcur (the degree-bin cursors)
__global__ __launch_bounds__(256) void p4_scan(
    const int* __restrict__ dhist, int* __restrict__ dcur)
{
    __shared__ int wpart[4];
    const int t = threadIdx.x, lane = t & 63, w = t >> 6;
    int v = dhist[t];
    int s = v;
#pragma unroll
    for (int off = 1; off < 64; off <<= 1) {
        int u = __shfl_up(s, off, 64);
        if (lane >= off) s += u;
    }
    if (lane == 63) wpart[w] = s;
    __syncthreads();
    int wex = 0;
#pragma unroll
    for (int i = 0; i < 3; ++i) if (i < w) wex += wpart[i];
    dcur[t] = wex + s - v;
}

// perm groups dsts by equal degree -> divergence-free prop waves.
// Order within a bin is nondeterministic (atomic cursor) but output is per-dst.
__global__ __launch_bounds__(256) void p5_perm(
    const int* __restrict__ offsets, int* __restrict__ dcur,
    int* __restrict__ perm, int N)
{
    const int d = blockIdx.x * 256 + threadIdx.x;
    if (d < N) {
        const int deg = offsets[d + 1] - offsets[d];
        const int pos = atomicAdd(&dcur[min(deg, DBINS - 1)], 1);
        perm[pos] = d;
    }
}

// ---------------- GEMM via MFMA (fp32 emulated with bf16 hi/lo split) ----------------
// Output hn is fp16 (normalized rows), nrm holds f32 L2 norms.
__global__ __launch_bounds__(256) void gemm_mfma_k(
    const float* __restrict__ x, const float* __restrict__ W,
    const float* __restrict__ b, unsigned short* __restrict__ hn,
    float* __restrict__ nrm, int n)
{
    __shared__ uint4 sB[2][4][4][64];   // [hi/lo][kc][nt][lane] = 32 KB
    for (int idx = threadIdx.x; idx < 2048; idx += 256) {
        int lanei = idx & 63;
        int f = idx >> 6;
        int nt = f & 3, kc = (f >> 2) & 3, hl = f >> 4;
        int col = nt * 16 + (lanei & 15);
        int kb  = kc * 32 + (lanei >> 4) * 8;
        unsigned u[4];
#pragma unroll
        for (int jj = 0; jj < 4; ++jj) {
            unsigned short h0, l0, h1, l1;
            split_bf16(W[(size_t)(kb + 2 * jj)     * HDIM + col], h0, l0);
            split_bf16(W[(size_t)(kb + 2 * jj + 1) * HDIM + col], h1, l1);
            u[jj] = hl ? ((unsigned)l0 | ((unsigned)l1 << 16))
                       : ((unsigned)h0 | ((unsigned)h1 << 16));
        }
        uint4 q; q.x = u[0]; q.y = u[1]; q.z = u[2]; q.w = u[3];
        sB[hl][kc][nt][lanei] = q;
    }
    __syncthreads();

    const int lane = threadIdx.x & 63;
    const int l15 = lane & 15, l4 = lane >> 4;
    const int gw = (int)((blockIdx.x * 256 + threadIdx.x) >> 6);
    const int nw = (int)((gridDim.x * 256) >> 6);
    const int ntiles = (n + 15) >> 4;

    const float bc0 = b[l15], bc1 = b[16 + l15], bc2 = b[32 + l15], bc3 = b[48 + l15];

    for (int tile = gw; tile < ntiles; tile += nw) {
        const int rowbase = tile << 4;
        int arow = rowbase + l15; if (arow >= n) arow = n - 1;
        const float* xp = x + (size_t)arow * FIN + l4 * 8;

        f32x4 acc0 = {bc0, bc0, bc0, bc0};
        f32x4 acc1 = {bc1, bc1, bc1, bc1};
        f32x4 acc2 = {bc2, bc2, bc2, bc2};
        f32x4 acc3 = {bc3, bc3, bc3, bc3};

#pragma unroll
        for (int kc = 0; kc < 4; ++kc) {
            float4 xa = *(const float4*)(xp + kc * 32);
            float4 xb = *(const float4*)(xp + kc * 32 + 4);
            float v[8] = {xa.x, xa.y, xa.z, xa.w, xb.x, xb.y, xb.z, xb.w};
            short8_t ah, al;
#pragma unroll
            for (int j = 0; j < 8; ++j) {
                unsigned bb = __builtin_bit_cast(unsigned, v[j]);
                ah[j] = (short)(bb >> 16);
                float fl = v[j] - __builtin_bit_cast(float, bb & 0xFFFF0000u);
                al[j] = (short)(__builtin_bit_cast(unsigned, fl) >> 16);
            }
#pragma unroll
            for (int nt = 0; nt < 4; ++nt) {
                short8_t bh = __builtin_bit_cast(short8_t, sB[0][kc][nt][lane]);
                short8_t bl = __builtin_bit_cast(short8_t, sB[1][kc][nt][lane]);
                f32x4* pacc = (nt == 0) ? &acc0 : (nt == 1) ? &acc1 : (nt == 2) ? &acc2 : &acc3;
                *pacc = __builtin_amdgcn_mfma_f32_16x16x32_bf16(ah, bh, *pacc, 0, 0, 0);
                *pacc = __builtin_amdgcn_mfma_f32_16x16x32_bf16(al, bh, *pacc, 0, 0, 0);
                *pacc = __builtin_amdgcn_mfma_f32_16x16x32_bf16(ah, bl, *pacc, 0, 0, 0);
            }
        }

        float ss0 = acc0.x*acc0.x + acc1.x*acc1.x + acc2.x*acc2.x + acc3.x*acc3.x;
        float ss1 = acc0.y*acc0.y + acc1.y*acc1.y + acc2.y*acc2.y + acc3.y*acc3.y;
        float ss2 = acc0.z*acc0.z + acc1.z*acc1.z + acc2.z*acc2.z + acc3.z*acc3.z;
        float ss3 = acc0.w*acc0.w + acc1.w*acc1.w + acc2.w*acc2.w + acc3.w*acc3.w;
#pragma unroll
        for (int m = 1; m < 16; m <<= 1) {
            ss0 += __shfl_xor(ss0, m, 64);
            ss1 += __shfl_xor(ss1, m, 64);
            ss2 += __shfl_xor(ss2, m, 64);
            ss3 += __shfl_xor(ss3, m, 64);
        }
        float n0 = sqrtf(ss0), n1 = sqrtf(ss1), n2 = sqrtf(ss2), n3 = sqrtf(ss3);
        float r0 = 1.0f / fmaxf(n0, 1e-12f), r1 = 1.0f / fmaxf(n1, 1e-12f);
        float r2 = 1.0f / fmaxf(n2, 1e-12f), r3 = 1.0f / fmaxf(n3, 1e-12f);
        const int rowb = rowbase + l4 * 4;
        if (l15 == 0) {
            if (rowb + 0 < n) nrm[rowb + 0] = n0;
            if (rowb + 1 < n) nrm[rowb + 1] = n1;
            if (rowb + 2 < n) nrm[rowb + 2] = n2;
            if (rowb + 3 < n) nrm[rowb + 3] = n3;
        }
#pragma unroll
        for (int nt = 0; nt < 4; ++nt) {
            f32x4 a = (nt == 0) ? acc0 : (nt == 1) ? acc1 : (nt == 2) ? acc2 : acc3;
            const int col = nt * 16 + l15;
            if (rowb + 0 < n) hn[(size_t)(rowb + 0) * HDIM + col] = f2h1(a.x * r0);
            if (rowb + 1 < n) hn[(size_t)(rowb + 1) * HDIM + col] = f2h1(a.y * r1);
            if (rowb + 2 < n) hn[(size_t)(rowb + 2) * HDIM + col] = f2h1(a.z * r2);
            if (rowb + 3 < n) hn[(size_t)(rowb + 3) * HDIM + col] = f2h1(a.w * r3);
        }
    }
}

// ---------------- AGNN propagation: 8-lane subgroup owns one dst (degree-binned) ----
// slot -> perm[slot] groups equal-degree dsts into the same wave: no divergence.
__global__ __launch_bounds__(256) void prop_k(
    const unsigned short* __restrict__ hn, const float* __restrict__ nrm,
    const int* __restrict__ offsets, const int* __restrict__ csr,
    const int* __restrict__ perm, const float* __restrict__ beta_ptr,
    unsigned short* __restrict__ hn_out, float* __restrict__ nrm_out,
    float* __restrict__ lsm_out, int n)
{
    const int lane = threadIdx.x & 63;
    const int sl = lane & 7;
    const int wid = (int)((blockIdx.x * 256 + threadIdx.x) >> 6);
    const int slot = wid * 8 + (lane >> 3);
    const bool dvalid = slot < n;
    const int d = perm[dvalid ? slot : (n - 1)];
    const float beta = beta_ptr ? beta_ptr[0] : 1.0f;
    const float shift = fabsf(beta);

    const uint4 hdu = *(const uint4*)(hn + ((size_t)d << 6) + (sl << 3));
    float hd[8];
    { float2 f0 = h2f2(hdu.x), f1 = h2f2(hdu.y), f2 = h2f2(hdu.z), f3 = h2f2(hdu.w);
      hd[0]=f0.x; hd[1]=f0.y; hd[2]=f1.x; hd[3]=f1.y;
      hd[4]=f2.x; hd[5]=f2.y; hd[6]=f3.x; hd[7]=f3.y; }

    const int i0 = offsets[d], i1 = offsets[d + 1];
    float acc[8] = {0,0,0,0,0,0,0,0};
    float ssum = 0.f;

    int e = i0;
    for (; e + 1 < i1; e += 2) {
        const int s0 = csr[e], s1 = csr[e + 1];
        const uint4 va = *(const uint4*)(hn + ((size_t)s0 << 6) + (sl << 3));
        const uint4 vb = *(const uint4*)(hn + ((size_t)s1 << 6) + (sl << 3));
        const float na = nrm[s0], nb = nrm[s1];
        float p0 = dot8(va, hd);
        float p1 = dot8(vb, hd);
        p0 += __shfl_xor(p0, 1, 64); p1 += __shfl_xor(p1, 1, 64);
        p0 += __shfl_xor(p0, 2, 64); p1 += __shfl_xor(p1, 2, 64);
        p0 += __shfl_xor(p0, 4, 64); p1 += __shfl_xor(p1, 4, 64);
        const float ev0 = __expf(beta * p0 - shift);
        const float ev1 = __expf(beta * p1 - shift);
        acc8(ev0 * na, va, acc);
        acc8(ev1 * nb, vb, acc);
        ssum += ev0 + ev1;
    }
    if (e < i1) {
        const int s0 = csr[e];
        const uint4 va = *(const uint4*)(hn + ((size_t)s0 << 6) + (sl << 3));
        const float na = nrm[s0];
        float p0 = dot8(va, hd);
        p0 += __shfl_xor(p0, 1, 64);
        p0 += __shfl_xor(p0, 2, 64);
        p0 += __shfl_xor(p0, 4, 64);
        const float ev0 = __expf(beta * p0 - shift);
        acc8(ev0 * na, va, acc);
        ssum += ev0;
    }

    const float rs = 1.0f / ssum;      // self loop => ssum > 0
    float o[8];
#pragma unroll
    for (int j = 0; j < 8; ++j) o[j] = acc[j] * rs;

    if (lsm_out) {
        float mx = o[0];
#pragma unroll
        for (int j = 1; j < 8; ++j) mx = fmaxf(mx, o[j]);
        mx = fmaxf(mx, __shfl_xor(mx, 1, 64));
        mx = fmaxf(mx, __shfl_xor(mx, 2, 64));
        mx = fmaxf(mx, __shfl_xor(mx, 4, 64));
        float es = 0.f;
#pragma unroll
        for (int j = 0; j < 8; ++j) es += __expf(o[j] - mx);
        es += __shfl_xor(es, 1, 64);
        es += __shfl_xor(es, 2, 64);
        es += __shfl_xor(es, 4, 64);
        const float ls = mx + __logf(es);
        if (dvalid) {
            float* op = lsm_out + ((size_t)d << 6) + (sl << 3);
            *(float4*)(op)     = make_float4(o[0]-ls, o[1]-ls, o[2]-ls, o[3]-ls);
            *(float4*)(op + 4) = make_float4(o[4]-ls, o[5]-ls, o[6]-ls, o[7]-ls);
        }
    } else {
        float ss = 0.f;
#pragma unroll
        for (int j = 0; j < 8; ++j) ss = fmaf(o[j], o[j], ss);
        ss += __shfl_xor(ss, 1, 64);
        ss += __shfl_xor(ss, 2, 64);
        ss += __shfl_xor(ss, 4, 64);
        const float norm = sqrtf(ss);
        const float rinv = 1.0f / fmaxf(norm, 1e-12f);
        if (dvalid) {
            uint4 q;
            q.x = f2h2(o[0] * rinv, o[1] * rinv);
            q.y = f2h2(o[2] * rinv, o[3] * rinv);
            q.z = f2h2(o[4] * rinv, o[5] * rinv);
            q.w = f2h2(o[6] * rinv, o[7] * rinv);
            *(uint4*)(hn_out + ((size_t)d << 6) + (sl << 3)) = q;
            if (sl == 0) nrm_out[d] = norm;
        }
    }
}

extern "C" void kernel_launch(void* const* d_in, const int* in_sizes, int n_in,
                              void* d_out, int out_size, void* d_ws, size_t ws_size,
                              hipStream_t stream)
{
    const float* x     = (const float*)d_in[0];
    const int*   ei    = (const int*)d_in[1];   // [2, E] int32
    const float* W1    = (const float*)d_in[2];
    const float* b1    = (const float*)d_in[3];
    const float* beta2 = (const float*)d_in[4];
    float* out = (float*)d_out;

    const int N    = in_sizes[0] / FIN;
    const int E    = in_sizes[1] / 2;
    const int Etot = E + N;
    const int NB   = (N + B2 - 1) >> B2SHIFT;          // 196 coarse buckets
    const int nblk = (Etot + EB - 1) / EB;             // 208 edge blocks

    // ws layout: hn1h[N*64 u16] hn2h[N*64 u16] nrm1[N] nrm2[N]
    //            offsets[N+1] csr[Etot] ph[256*nblk] bbase[257] btot[256]
    //            dhist[256] dcur[256] perm[N]
    // pairs (u32, Etot = 6.8 MB) ALIASES hn2h (12.8 MB): dead before prop1 writes.
    unsigned short* hn1h = (unsigned short*)d_ws;
    unsigned short* hn2h = hn1h + (size_t)N * HDIM;
    float* nrm1    = (float*)(hn2h + (size_t)N * HDIM);
    float* nrm2    = nrm1 + N;
    int*   offsets = (int*)(nrm2 + N);
    int*   csr     = offsets + (N + 1);
    int*   ph      = csr + Etot;
    int*   bbase   = ph + 256 * nblk;
    int*   btot    = bbase + 257;
    int*   dhist   = btot + 256;
    int*   dcur    = dhist + DBINS;
    int*   perm    = dcur + DBINS;
    unsigned* pairs = (unsigned*)hn2h;

    const dim3 blk(256);

    // ---- CSR build (deterministic counting sort; no global data atomics) ----
    hipMemsetAsync(dhist, 0, DBINS * sizeof(int), stream);
    p1_hist<<<nblk, blk, 0, stream>>>(ei, ph, E, Etot, NB, nblk);
    p1_scanA<<<NB, blk, 0, stream>>>(ph, btot, nblk);
    p1_scanB<<<1, blk, 0, stream>>>(btot, bbase, offsets, NB, N);
    p2_scatter<<<nblk, blk, 0, stream>>>(ei, ph, bbase, pairs, E, Etot, NB, nblk);
    p3_csr<<<NB, blk, 0, stream>>>(pairs, bbase, offsets, csr, dhist, N);

    // ---- degree-binned dst permutation for divergence-free prop waves ----
    p4_scan<<<1, blk, 0, stream>>>(dhist, dcur);
    p5_perm<<<(N + 255) / 256, blk, 0, stream>>>(offsets, dcur, perm, N);

    // ---- h = x@W1+b1 (MFMA), normalized, fp16 ----
    const int ntiles = (N + 15) >> 4;
    gemm_mfma_k<<<(ntiles + 3) / 4, blk, 0, stream>>>(x, W1, b1, hn1h, nrm1, N);

    // ---- props: 8 dsts per wave, 32 per block ----
    const int pblocks = (N + 31) / 32;
    prop_k<<<pblocks, blk, 0, stream>>>(hn1h, nrm1, offsets, csr, perm, nullptr,
                                        hn2h, nrm2, nullptr, N);
    prop_k<<<pblocks, blk, 0, stream>>>(hn2h, nrm2, offsets, csr, perm, beta2,
                                        nullptr, nullptr, out, N);
}

// Round 8
// 265.151 us; speedup vs baseline: 3.1567x; 3.1567x over previous
//
#include <hip/hip_runtime.h>
#include <math.h>

#define FIN 128
#define HDIM 64

// CSR-build (counting sort) geometry. Assumes N <= 131072 (src fits 17 bits,
// coarse buckets <= 256), Etot <= 2.09M (nblk <= 256). Instance: N=100k, E=1.6M.
#define EB 8192            // edges per block in p1/p2
#define B2SHIFT 9
#define B2 (1 << B2SHIFT)  // 512 dst per coarse bucket
#define SRCBITS 17
#define SRCMASK ((1u << SRCBITS) - 1u)
#define DBINS 256          // degree bins for the prop scheduling sort
#define DEB 2048           // dsts per block in the degree sort

typedef __attribute__((ext_vector_type(8))) short short8_t;  // 8 bf16 (4 VGPRs)
typedef __attribute__((ext_vector_type(4))) float f32x4;
typedef _Float16 h2_t __attribute__((ext_vector_type(2)));

__device__ __forceinline__ float2 h2f2(unsigned u) {
    h2_t h = __builtin_bit_cast(h2_t, u);
    return make_float2((float)h.x, (float)h.y);
}
__device__ __forceinline__ unsigned f2h2(float a, float b) {
    h2_t h; h.x = (_Float16)a; h.y = (_Float16)b;
    return __builtin_bit_cast(unsigned, h);
}
__device__ __forceinline__ unsigned short f2h1(float a) {
    _Float16 h = (_Float16)a;
    return __builtin_bit_cast(unsigned short, h);
}

__device__ __forceinline__ void split_bf16(float f, unsigned short& hi, unsigned short& lo) {
    unsigned b = __builtin_bit_cast(unsigned, f);
    hi = (unsigned short)(b >> 16);
    float fh = __builtin_bit_cast(float, b & 0xFFFF0000u);
    float fl = f - fh;
    lo = (unsigned short)(__builtin_bit_cast(unsigned, fl) >> 16);
}

// 8-wide dot of packed fp16 against f32-promoted: compiler emits v_fma_mix_f32.
__device__ __forceinline__ float dot8(uint4 v, const float* hd) {
    float2 a = h2f2(v.x), b = h2f2(v.y), c = h2f2(v.z), d = h2f2(v.w);
    float p = a.x * hd[0];
    p = fmaf(a.y, hd[1], p);
    p = fmaf(b.x, hd[2], p);
    p = fmaf(b.y, hd[3], p);
    p = fmaf(c.x, hd[4], p);
    p = fmaf(c.y, hd[5], p);
    p = fmaf(d.x, hd[6], p);
    p = fmaf(d.y, hd[7], p);
    return p;
}
__device__ __forceinline__ void acc8(float w, uint4 v, float* a) {
    float2 f0 = h2f2(v.x), f1 = h2f2(v.y), f2 = h2f2(v.z), f3 = h2f2(v.w);
    a[0] = fmaf(w, f0.x, a[0]); a[1] = fmaf(w, f0.y, a[1]);
    a[2] = fmaf(w, f1.x, a[2]); a[3] = fmaf(w, f1.y, a[3]);
    a[4] = fmaf(w, f2.x, a[4]); a[5] = fmaf(w, f2.y, a[5]);
    a[6] = fmaf(w, f3.x, a[6]); a[7] = fmaf(w, f3.y, a[7]);
}

// ---------------- CSR build: deterministic two-level counting sort ----------------

__global__ __launch_bounds__(256) void p1_hist(
    const int* __restrict__ ei, int* __restrict__ ph,
    int E, int Etot, int NB, int nblk)
{
    __shared__ int h[256];
    h[threadIdx.x] = 0;
    __syncthreads();
    const int base = blockIdx.x * EB;
    const int end = min(base + EB, Etot);
    for (int e = base + (int)threadIdx.x; e < end; e += 256) {
        int d = (e < E) ? ei[E + e] : (e - E);
        atomicAdd(&h[d >> B2SHIFT], 1);
    }
    __syncthreads();
    if ((int)threadIdx.x < NB) ph[threadIdx.x * nblk + blockIdx.x] = h[threadIdx.x];
}

// One block per bucket: exclusive scan of ph[b][0..nblk) in place, total -> btot[b]
__global__ __launch_bounds__(256) void p1_scanA(
    int* __restrict__ ph, int* __restrict__ btot, int nblk)
{
    __shared__ int wpart[4];
    const int b = blockIdx.x;
    const int t = threadIdx.x, lane = t & 63, w = t >> 6;
    int v = (t < nblk) ? ph[b * nblk + t] : 0;
    int s = v;
#pragma unroll
    for (int off = 1; off < 64; off <<= 1) {
        int u = __shfl_up(s, off, 64);
        if (lane >= off) s += u;
    }
    if (lane == 63) wpart[w] = s;
    __syncthreads();
    int wex = 0;
#pragma unroll
    for (int i = 0; i < 3; ++i) if (i < w) wex += wpart[i];
    if (t < nblk) ph[b * nblk + t] = wex + s - v;
    if (t == 255) btot[b] = wex + s;
}

// Single tiny block: scan bucket totals -> bbase[NB+1]; offsets[N] = Etot.
__global__ __launch_bounds__(256) void p1_scanB(
    const int* __restrict__ btot, int* __restrict__ bbase,
    int* __restrict__ offsets, int NB, int N)
{
    __shared__ int wpart[4];
    const int t = threadIdx.x, lane = t & 63, w = t >> 6;
    int v = (t < NB) ? btot[t] : 0;
    int s = v;
#pragma unroll
    for (int off = 1; off < 64; off <<= 1) {
        int u = __shfl_up(s, off, 64);
        if (lane >= off) s += u;
    }
    if (lane == 63) wpart[w] = s;
    __syncthreads();
    int wex = 0;
#pragma unroll
    for (int i = 0; i < 3; ++i) if (i < w) wex += wpart[i];
    if (t < NB) bbase[t] = wex + s - v;
    if (t == 255) { bbase[NB] = wex + s; offsets[N] = wex + s; }
}

__global__ __launch_bounds__(256) void p2_scatter(
    const int* __restrict__ ei, const int* __restrict__ ph,
    const int* __restrict__ bbase, unsigned* __restrict__ pairs,
    int E, int Etot, int NB, int nblk)
{
    __shared__ int cur[256];
    if ((int)threadIdx.x < NB)
        cur[threadIdx.x] = bbase[threadIdx.x] + ph[threadIdx.x * nblk + blockIdx.x];
    __syncthreads();
    const int base = blockIdx.x * EB;
    const int end = min(base + EB, Etot);
    for (int e = base + (int)threadIdx.x; e < end; e += 256) {
        int s, d;
        if (e < E) { s = ei[e]; d = ei[E + e]; }
        else       { s = e - E; d = s; }
        int pos = atomicAdd(&cur[d >> B2SHIFT], 1);
        pairs[pos] = ((unsigned)(d & (B2 - 1)) << SRCBITS) | (unsigned)s;
    }
}

// One block (256 thr) per bucket: 512-bin LDS hist + scan -> offsets, then scatter.
__global__ __launch_bounds__(256) void p3_csr(
    const unsigned* __restrict__ pairs, const int* __restrict__ bbase,
    int* __restrict__ offsets, int* __restrict__ csr, int N)
{
    __shared__ int hist[B2];
    __shared__ int wp[4];
    const int b = blockIdx.x;
    const int p0 = bbase[b], p1 = bbase[b + 1];
    const int dbase = b << B2SHIFT;
    const int lane = threadIdx.x & 63, w = threadIdx.x >> 6;
    hist[threadIdx.x] = 0; hist[threadIdx.x + 256] = 0;
    __syncthreads();
    for (int i = p0 + (int)threadIdx.x; i < p1; i += 256)
        atomicAdd(&hist[pairs[i] >> SRCBITS], 1);
    __syncthreads();
    const int v0 = hist[2 * threadIdx.x], v1 = hist[2 * threadIdx.x + 1];
    const int t = v0 + v1;
    int s = t;
#pragma unroll
    for (int off = 1; off < 64; off <<= 1) {
        int u = __shfl_up(s, off, 64);
        if (lane >= off) s += u;
    }
    if (lane == 63) wp[w] = s;
    __syncthreads();
    int wex = 0;
#pragma unroll
    for (int i = 0; i < 3; ++i) if (i < w) wex += wp[i];
    const int tex = wex + (s - t);
    const int e0 = tex, e1 = tex + v0;
    const int d0 = dbase + 2 * (int)threadIdx.x, d1 = d0 + 1;
    if (d0 < N) offsets[d0] = p0 + e0;
    if (d1 < N) offsets[d1] = p0 + e1;
    __syncthreads();
    hist[2 * threadIdx.x] = e0; hist[2 * threadIdx.x + 1] = e1;
    __syncthreads();
    for (int i = p0 + (int)threadIdx.x; i < p1; i += 256) {
        unsigned pk = pairs[i];
        int pos = p0 + atomicAdd(&hist[pk >> SRCBITS], 1);
        csr[pos] = (int)(pk & SRCMASK);
    }
}

// ---------------- degree sort (contention-free counting sort over dsts) ----------

// Per-block LDS degree histogram -> dpart[bin][blk] (plain writes, no global atomics)
__global__ __launch_bounds__(256) void pd_hist(
    const int* __restrict__ offsets, int* __restrict__ dpart, int nblkd, int N)
{
    __shared__ int h[DBINS];
    h[threadIdx.x] = 0;
    __syncthreads();
    const int base = blockIdx.x * DEB;
    const int end = min(base + DEB, N);
    for (int d = base + (int)threadIdx.x; d < end; d += 256) {
        int deg = offsets[d + 1] - offsets[d];
        atomicAdd(&h[min(deg, DBINS - 1)], 1);     // LDS atomic
    }
    __syncthreads();
    dpart[threadIdx.x * nblkd + blockIdx.x] = h[threadIdx.x];
}

// One block per bin: exclusive scan of dpart[bin][0..nblkd) in place, total -> dtot
__global__ __launch_bounds__(256) void pd_scanA(
    int* __restrict__ dpart, int* __restrict__ dtot, int nblkd)
{
    __shared__ int wpart[4];
    const int b = blockIdx.x;
    const int t = threadIdx.x, lane = t & 63, w = t >> 6;
    int v = (t < nblkd) ? dpart[b * nblkd + t] : 0;
    int s = v;
#pragma unroll
    for (int off = 1; off < 64; off <<= 1) {
        int u = __shfl_up(s, off, 64);
        if (lane >= off) s += u;
    }
    if (lane == 63) wpart[w] = s;
    __syncthreads();
    int wex = 0;
#pragma unroll
    for (int i = 0; i < 3; ++i) if (i < w) wex += wpart[i];
    if (t < nblkd) dpart[b * nblkd + t] = wex + s - v;
    if (t == 255) dtot[b] = wex + s;
}

// Single tiny block: exclusive scan of dtot[256] -> dbase
__global__ __launch_bounds__(256) void pd_scanB(
    const int* __restrict__ dtot, int* __restrict__ dbase)
{
    __shared__ int wpart[4];
    const int t = threadIdx.x, lane = t & 63, w = t >> 6;
    int v = dtot[t];
    int s = v;
#pragma unroll
    for (int off = 1; off < 64; off <<= 1) {
        int u = __shfl_up(s, off, 64);
        if (lane >= off) s += u;
    }
    if (lane == 63) wpart[w] = s;
    __syncthreads();
    int wex = 0;
#pragma unroll
    for (int i = 0; i < 3; ++i) if (i < w) wex += wpart[i];
    dbase[t] = wex + s - v;
}

// Scatter dsts into degree-sorted perm via LDS cursors (block-local atomics only)
__global__ __launch_bounds__(256) void pd_perm(
    const int* __restrict__ offsets, const int* __restrict__ dpart,
    const int* __restrict__ dbase, int* __restrict__ perm, int nblkd, int N)
{
    __shared__ int cur[DBINS];
    cur[threadIdx.x] = dbase[threadIdx.x] + dpart[threadIdx.x * nblkd + blockIdx.x];
    __syncthreads();
    const int base = blockIdx.x * DEB;
    const int end = min(base + DEB, N);
    for (int d = base + (int)threadIdx.x; d < end; d += 256) {
        int deg = offsets[d + 1] - offsets[d];
        int pos = atomicAdd(&cur[min(deg, DBINS - 1)], 1);   // LDS atomic
        perm[pos] = d;
    }
}

// ---------------- GEMM via MFMA (fp32 emulated with bf16 hi/lo split) ----------------
// Output hn is fp16 (normalized rows), nrm holds f32 L2 norms.
__global__ __launch_bounds__(256) void gemm_mfma_k(
    const float* __restrict__ x, const float* __restrict__ W,
    const float* __restrict__ b, unsigned short* __restrict__ hn,
    float* __restrict__ nrm, int n)
{
    __shared__ uint4 sB[2][4][4][64];   // [hi/lo][kc][nt][lane] = 32 KB
    for (int idx = threadIdx.x; idx < 2048; idx += 256) {
        int lanei = idx & 63;
        int f = idx >> 6;
        int nt = f & 3, kc = (f >> 2) & 3, hl = f >> 4;
        int col = nt * 16 + (lanei & 15);
        int kb  = kc * 32 + (lanei >> 4) * 8;
        unsigned u[4];
#pragma unroll
        for (int jj = 0; jj < 4; ++jj) {
            unsigned short h0, l0, h1, l1;
            split_bf16(W[(size_t)(kb + 2 * jj)     * HDIM + col], h0, l0);
            split_bf16(W[(size_t)(kb + 2 * jj + 1) * HDIM + col], h1, l1);
            u[jj] = hl ? ((unsigned)l0 | ((unsigned)l1 << 16))
                       : ((unsigned)h0 | ((unsigned)h1 << 16));
        }
        uint4 q; q.x = u[0]; q.y = u[1]; q.z = u[2]; q.w = u[3];
        sB[hl][kc][nt][lanei] = q;
    }
    __syncthreads();

    const int lane = threadIdx.x & 63;
    const int l15 = lane & 15, l4 = lane >> 4;
    const int gw = (int)((blockIdx.x * 256 + threadIdx.x) >> 6);
    const int nw = (int)((gridDim.x * 256) >> 6);
    const int ntiles = (n + 15) >> 4;

    const float bc0 = b[l15], bc1 = b[16 + l15], bc2 = b[32 + l15], bc3 = b[48 + l15];

    for (int tile = gw; tile < ntiles; tile += nw) {
        const int rowbase = tile << 4;
        int arow = rowbase + l15; if (arow >= n) arow = n - 1;
        const float* xp = x + (size_t)arow * FIN + l4 * 8;

        f32x4 acc0 = {bc0, bc0, bc0, bc0};
        f32x4 acc1 = {bc1, bc1, bc1, bc1};
        f32x4 acc2 = {bc2, bc2, bc2, bc2};
        f32x4 acc3 = {bc3, bc3, bc3, bc3};

#pragma unroll
        for (int kc = 0; kc < 4; ++kc) {
            float4 xa = *(const float4*)(xp + kc * 32);
            float4 xb = *(const float4*)(xp + kc * 32 + 4);
            float v[8] = {xa.x, xa.y, xa.z, xa.w, xb.x, xb.y, xb.z, xb.w};
            short8_t ah, al;
#pragma unroll
            for (int j = 0; j < 8; ++j) {
                unsigned bb = __builtin_bit_cast(unsigned, v[j]);
                ah[j] = (short)(bb >> 16);
                float fl = v[j] - __builtin_bit_cast(float, bb & 0xFFFF0000u);
                al[j] = (short)(__builtin_bit_cast(unsigned, fl) >> 16);
            }
#pragma unroll
            for (int nt = 0; nt < 4; ++nt) {
                short8_t bh = __builtin_bit_cast(short8_t, sB[0][kc][nt][lane]);
                short8_t bl = __builtin_bit_cast(short8_t, sB[1][kc][nt][lane]);
                f32x4* pacc = (nt == 0) ? &acc0 : (nt == 1) ? &acc1 : (nt == 2) ? &acc2 : &acc3;
                *pacc = __builtin_amdgcn_mfma_f32_16x16x32_bf16(ah, bh, *pacc, 0, 0, 0);
                *pacc = __builtin_amdgcn_mfma_f32_16x16x32_bf16(al, bh, *pacc, 0, 0, 0);
                *pacc = __builtin_amdgcn_mfma_f32_16x16x32_bf16(ah, bl, *pacc, 0, 0, 0);
            }
        }

        float ss0 = acc0.x*acc0.x + acc1.x*acc1.x + acc2.x*acc2.x + acc3.x*acc3.x;
        float ss1 = acc0.y*acc0.y + acc1.y*acc1.y + acc2.y*acc2.y + acc3.y*acc3.y;
        float ss2 = acc0.z*acc0.z + acc1.z*acc1.z + acc2.z*acc2.z + acc3.z*acc3.z;
        float ss3 = acc0.w*acc0.w + acc1.w*acc1.w + acc2.w*acc2.w + acc3.w*acc3.w;
#pragma unroll
        for (int m = 1; m < 16; m <<= 1) {
            ss0 += __shfl_xor(ss0, m, 64);
            ss1 += __shfl_xor(ss1, m, 64);
            ss2 += __shfl_xor(ss2, m, 64);
            ss3 += __shfl_xor(ss3, m, 64);
        }
        float n0 = sqrtf(ss0), n1 = sqrtf(ss1), n2 = sqrtf(ss2), n3 = sqrtf(ss3);
        float r0 = 1.0f / fmaxf(n0, 1e-12f), r1 = 1.0f / fmaxf(n1, 1e-12f);
        float r2 = 1.0f / fmaxf(n2, 1e-12f), r3 = 1.0f / fmaxf(n3, 1e-12f);
        const int rowb = rowbase + l4 * 4;
        if (l15 == 0) {
            if (rowb + 0 < n) nrm[rowb + 0] = n0;
            if (rowb + 1 < n) nrm[rowb + 1] = n1;
            if (rowb + 2 < n) nrm[rowb + 2] = n2;
            if (rowb + 3 < n) nrm[rowb + 3] = n3;
        }
#pragma unroll
        for (int nt = 0; nt < 4; ++nt) {
            f32x4 a = (nt == 0) ? acc0 : (nt == 1) ? acc1 : (nt == 2) ? acc2 : acc3;
            const int col = nt * 16 + l15;
            if (rowb + 0 < n) hn[(size_t)(rowb + 0) * HDIM + col] = f2h1(a.x * r0);
            if (rowb + 1 < n) hn[(size_t)(rowb + 1) * HDIM + col] = f2h1(a.y * r1);
            if (rowb + 2 < n) hn[(size_t)(rowb + 2) * HDIM + col] = f2h1(a.z * r2);
            if (rowb + 3 < n) hn[(size_t)(rowb + 3) * HDIM + col] = f2h1(a.w * r3);
        }
    }
}

// ---------------- AGNN propagation: 8-lane subgroup owns one dst (degree-binned) ----
__global__ __launch_bounds__(256) void prop_k(
    const unsigned short* __restrict__ hn, const float* __restrict__ nrm,
    const int* __restrict__ offsets, const int* __restrict__ csr,
    const int* __restrict__ perm, const float* __restrict__ beta_ptr,
    unsigned short* __restrict__ hn_out, float* __restrict__ nrm_out,
    float* __restrict__ lsm_out, int n)
{
    const int lane = threadIdx.x & 63;
    const int sl = lane & 7;
    const int wid = (int)((blockIdx.x * 256 + threadIdx.x) >> 6);
    const int slot = wid * 8 + (lane >> 3);
    const bool dvalid = slot < n;
    const int d = perm[dvalid ? slot : (n - 1)];
    const float beta = beta_ptr ? beta_ptr[0] : 1.0f;
    const float shift = fabsf(beta);

    const uint4 hdu = *(const uint4*)(hn + ((size_t)d << 6) + (sl << 3));
    float hd[8];
    { float2 f0 = h2f2(hdu.x), f1 = h2f2(hdu.y), f2 = h2f2(hdu.z), f3 = h2f2(hdu.w);
      hd[0]=f0.x; hd[1]=f0.y; hd[2]=f1.x; hd[3]=f1.y;
      hd[4]=f2.x; hd[5]=f2.y; hd[6]=f3.x; hd[7]=f3.y; }

    const int i0 = offsets[d], i1 = offsets[d + 1];
    float acc[8] = {0,0,0,0,0,0,0,0};
    float ssum = 0.f;

    int e = i0;
    for (; e + 1 < i1; e += 2) {
        const int s0 = csr[e], s1 = csr[e + 1];
        const uint4 va = *(const uint4*)(hn + ((size_t)s0 << 6) + (sl << 3));
        const uint4 vb = *(const uint4*)(hn + ((size_t)s1 << 6) + (sl << 3));
        const float na = nrm[s0], nb = nrm[s1];
        float p0 = dot8(va, hd);
        float p1 = dot8(vb, hd);
        p0 += __shfl_xor(p0, 1, 64); p1 += __shfl_xor(p1, 1, 64);
        p0 += __shfl_xor(p0, 2, 64); p1 += __shfl_xor(p1, 2, 64);
        p0 += __shfl_xor(p0, 4, 64); p1 += __shfl_xor(p1, 4, 64);
        const float ev0 = __expf(beta * p0 - shift);
        const float ev1 = __expf(beta * p1 - shift);
        acc8(ev0 * na, va, acc);
        acc8(ev1 * nb, vb, acc);
        ssum += ev0 + ev1;
    }
    if (e < i1) {
        const int s0 = csr[e];
        const uint4 va = *(const uint4*)(hn + ((size_t)s0 << 6) + (sl << 3));
        const float na = nrm[s0];
        float p0 = dot8(va, hd);
        p0 += __shfl_xor(p0, 1, 64);
        p0 += __shfl_xor(p0, 2, 64);
        p0 += __shfl_xor(p0, 4, 64);
        const float ev0 = __expf(beta * p0 - shift);
        acc8(ev0 * na, va, acc);
        ssum += ev0;
    }

    const float rs = 1.0f / ssum;      // self loop => ssum > 0
    float o[8];
#pragma unroll
    for (int j = 0; j < 8; ++j) o[j] = acc[j] * rs;

    if (lsm_out) {
        float mx = o[0];
#pragma unroll
        for (int j = 1; j < 8; ++j) mx = fmaxf(mx, o[j]);
        mx = fmaxf(mx, __shfl_xor(mx, 1, 64));
        mx = fmaxf(mx, __shfl_xor(mx, 2, 64));
        mx = fmaxf(mx, __shfl_xor(mx, 4, 64));
        float es = 0.f;
#pragma unroll
        for (int j = 0; j < 8; ++j) es += __expf(o[j] - mx);
        es += __shfl_xor(es, 1, 64);
        es += __shfl_xor(es, 2, 64);
        es += __shfl_xor(es, 4, 64);
        const float ls = mx + __logf(es);
        if (dvalid) {
            float* op = lsm_out + ((size_t)d << 6) + (sl << 3);
            *(float4*)(op)     = make_float4(o[0]-ls, o[1]-ls, o[2]-ls, o[3]-ls);
            *(float4*)(op + 4) = make_float4(o[4]-ls, o[5]-ls, o[6]-ls, o[7]-ls);
        }
    } else {
        float ss = 0.f;
#pragma unroll
        for (int j = 0; j < 8; ++j) ss = fmaf(o[j], o[j], ss);
        ss += __shfl_xor(ss, 1, 64);
        ss += __shfl_xor(ss, 2, 64);
        ss += __shfl_xor(ss, 4, 64);
        const float norm = sqrtf(ss);
        const float rinv = 1.0f / fmaxf(norm, 1e-12f);
        if (dvalid) {
            uint4 q;
            q.x = f2h2(o[0] * rinv, o[1] * rinv);
            q.y = f2h2(o[2] * rinv, o[3] * rinv);
            q.z = f2h2(o[4] * rinv, o[5] * rinv);
            q.w = f2h2(o[6] * rinv, o[7] * rinv);
            *(uint4*)(hn_out + ((size_t)d << 6) + (sl << 3)) = q;
            if (sl == 0) nrm_out[d] = norm;
        }
    }
}

extern "C" void kernel_launch(void* const* d_in, const int* in_sizes, int n_in,
                              void* d_out, int out_size, void* d_ws, size_t ws_size,
                              hipStream_t stream)
{
    const float* x     = (const float*)d_in[0];
    const int*   ei    = (const int*)d_in[1];   // [2, E] int32
    const float* W1    = (const float*)d_in[2];
    const float* b1    = (const float*)d_in[3];
    const float* beta2 = (const float*)d_in[4];
    float* out = (float*)d_out;

    const int N    = in_sizes[0] / FIN;
    const int E    = in_sizes[1] / 2;
    const int Etot = E + N;
    const int NB   = (N + B2 - 1) >> B2SHIFT;          // 196 coarse buckets
    const int nblk = (Etot + EB - 1) / EB;             // 208 edge blocks
    const int nblkd = (N + DEB - 1) / DEB;             // 49 dst blocks

    // ws layout: hn1h[N*64 u16] hn2h[N*64 u16] nrm1[N] nrm2[N]
    //            offsets[N+1] csr[Etot] ph[256*nblk] bbase[257] btot[256]
    //            dpart[256*nblkd] dtot[256] dbase[256] perm[N]
    // pairs (u32, Etot = 6.8 MB) ALIASES hn2h (12.8 MB): dead before prop1 writes.
    unsigned short* hn1h = (unsigned short*)d_ws;
    unsigned short* hn2h = hn1h + (size_t)N * HDIM;
    float* nrm1    = (float*)(hn2h + (size_t)N * HDIM);
    float* nrm2    = nrm1 + N;
    int*   offsets = (int*)(nrm2 + N);
    int*   csr     = offsets + (N + 1);
    int*   ph      = csr + Etot;
    int*   bbase   = ph + 256 * nblk;
    int*   btot    = bbase + 257;
    int*   dpart   = btot + 256;
    int*   dtot    = dpart + 256 * nblkd;
    int*   dbase   = dtot + 256;
    int*   perm    = dbase + 256;
    unsigned* pairs = (unsigned*)hn2h;

    const dim3 blk(256);

    // ---- CSR build (deterministic counting sort; no global data atomics) ----
    p1_hist<<<nblk, blk, 0, stream>>>(ei, ph, E, Etot, NB, nblk);
    p1_scanA<<<NB, blk, 0, stream>>>(ph, btot, nblk);
    p1_scanB<<<1, blk, 0, stream>>>(btot, bbase, offsets, NB, N);
    p2_scatter<<<nblk, blk, 0, stream>>>(ei, ph, bbase, pairs, E, Etot, NB, nblk);
    p3_csr<<<NB, blk, 0, stream>>>(pairs, bbase, offsets, csr, N);

    // ---- degree-binned dst permutation (contention-free counting sort) ----
    pd_hist<<<nblkd, blk, 0, stream>>>(offsets, dpart, nblkd, N);
    pd_scanA<<<DBINS, blk, 0, stream>>>(dpart, dtot, nblkd);
    pd_scanB<<<1, blk, 0, stream>>>(dtot, dbase);
    pd_perm<<<nblkd, blk, 0, stream>>>(offsets, dpart, dbase, perm, nblkd, N);

    // ---- h = x@W1+b1 (MFMA), normalized, fp16 ----
    const int ntiles = (N + 15) >> 4;
    gemm_mfma_k<<<(ntiles + 3) / 4, blk, 0, stream>>>(x, W1, b1, hn1h, nrm1, N);

    // ---- props: 8 dsts per wave, 32 per block ----
    const int pblocks = (N + 31) / 32;
    prop_k<<<pblocks, blk, 0, stream>>>(hn1h, nrm1, offsets, csr, perm, nullptr,
                                        hn2h, nrm2, nullptr, N);
    prop_k<<<pblocks, blk, 0, stream>>>(hn2h, nrm2, offsets, csr, perm, beta2,
                                        nullptr, nullptr, out, N);
}

// Round 9
// 250.475 us; speedup vs baseline: 3.3416x; 1.0586x over previous
//
#include <hip/hip_runtime.h>
#include <math.h>

#define FIN 128
#define HDIM 64

// CSR-build geometry. Assumes N <= 131072 (src fits 17 bits, buckets <= 256),
// Etot <= 2.09M (nblk <= 256). Instance: N=100k, E=1.6M, Etot=1.7M.
#define EB 8192            // edges per block in pc_scatter
#define B2SHIFT 9
#define B2 (1 << B2SHIFT)  // 512 dst per bucket
#define SRCBITS 17
#define SRCMASK ((1u << SRCBITS) - 1u)
#define CAP 12288          // padded bucket capacity (mean 9216, sigma ~96)

typedef __attribute__((ext_vector_type(8))) short short8_t;  // 8 bf16 (4 VGPRs)
typedef __attribute__((ext_vector_type(4))) float f32x4;
typedef _Float16 h2_t __attribute__((ext_vector_type(2)));

__device__ __forceinline__ float2 h2f2(unsigned u) {
    h2_t h = __builtin_bit_cast(h2_t, u);
    return make_float2((float)h.x, (float)h.y);
}
__device__ __forceinline__ unsigned f2h2(float a, float b) {
    h2_t h; h.x = (_Float16)a; h.y = (_Float16)b;
    return __builtin_bit_cast(unsigned, h);
}
__device__ __forceinline__ unsigned short f2h1(float a) {
    _Float16 h = (_Float16)a;
    return __builtin_bit_cast(unsigned short, h);
}

__device__ __forceinline__ void split_bf16(float f, unsigned short& hi, unsigned short& lo) {
    unsigned b = __builtin_bit_cast(unsigned, f);
    hi = (unsigned short)(b >> 16);
    float fh = __builtin_bit_cast(float, b & 0xFFFF0000u);
    float fl = f - fh;
    lo = (unsigned short)(__builtin_bit_cast(unsigned, fl) >> 16);
}

// 8-wide dot of packed fp16 against f32-promoted: compiler emits v_fma_mix_f32.
__device__ __forceinline__ float dot8(uint4 v, const float* hd) {
    float2 a = h2f2(v.x), b = h2f2(v.y), c = h2f2(v.z), d = h2f2(v.w);
    float p = a.x * hd[0];
    p = fmaf(a.y, hd[1], p);
    p = fmaf(b.x, hd[2], p);
    p = fmaf(b.y, hd[3], p);
    p = fmaf(c.x, hd[4], p);
    p = fmaf(c.y, hd[5], p);
    p = fmaf(d.x, hd[6], p);
    p = fmaf(d.y, hd[7], p);
    return p;
}
__device__ __forceinline__ void acc8(float w, uint4 v, float* a) {
    float2 f0 = h2f2(v.x), f1 = h2f2(v.y), f2 = h2f2(v.z), f3 = h2f2(v.w);
    a[0] = fmaf(w, f0.x, a[0]); a[1] = fmaf(w, f0.y, a[1]);
    a[2] = fmaf(w, f1.x, a[2]); a[3] = fmaf(w, f1.y, a[3]);
    a[4] = fmaf(w, f2.x, a[4]); a[5] = fmaf(w, f2.y, a[5]);
    a[6] = fmaf(w, f3.x, a[6]); a[7] = fmaf(w, f3.y, a[7]);
}

// ---------------- CSR build: padded-bucket counting sort (1 pass over ei) ------

// Fused hist + chunk-reserve + scatter. Per block: LDS hist over buckets,
// reserve [rsv, rsv+cnt) in bucket b's padded region via ONE global atomic per
// (block,bucket) (~208 adds per counter: uncontended), re-read edges (L2-hot)
// and scatter pairs via LDS cursors. pairs[b*CAP + i] = (dst_local<<17)|src.
__global__ __launch_bounds__(256) void pc_scatter(
    const int* __restrict__ ei, int* __restrict__ bcur,
    unsigned* __restrict__ pairs, int E, int Etot, int NB)
{
    __shared__ int h[256];
    h[threadIdx.x] = 0;
    __syncthreads();
    const int base = blockIdx.x * EB;
    const int end = min(base + EB, Etot);
    for (int e = base + (int)threadIdx.x; e < end; e += 256) {
        int d = (e < E) ? ei[E + e] : (e - E);
        atomicAdd(&h[d >> B2SHIFT], 1);           // LDS atomic
    }
    __syncthreads();
    const int cnt = h[threadIdx.x];
    int rsv = 0;
    if ((int)threadIdx.x < NB && cnt > 0)
        rsv = atomicAdd(&bcur[threadIdx.x], cnt); // global, ~208 adds/addr
    __syncthreads();
    h[threadIdx.x] = (int)threadIdx.x * CAP + rsv;  // chunk cursor
    __syncthreads();
    for (int e = base + (int)threadIdx.x; e < end; e += 256) {
        int s, d;
        if (e < E) { s = ei[e]; d = ei[E + e]; }
        else       { s = e - E; d = s; }
        int pos = atomicAdd(&h[d >> B2SHIFT], 1); // LDS atomic
        pairs[pos] = ((unsigned)(d & (B2 - 1)) << SRCBITS) | (unsigned)s;
    }
}

// Single tiny block: exclusive scan of bucket counts -> bbase[NB+1] (compacted
// csr bases); offsets[N] = Etot.
__global__ __launch_bounds__(256) void pc_scan(
    const int* __restrict__ bcur, int* __restrict__ bbase,
    int* __restrict__ offsets, int NB, int N)
{
    __shared__ int wpart[4];
    const int t = threadIdx.x, lane = t & 63, w = t >> 6;
    int v = (t < NB) ? bcur[t] : 0;
    int s = v;
#pragma unroll
    for (int off = 1; off < 64; off <<= 1) {
        int u = __shfl_up(s, off, 64);
        if (lane >= off) s += u;
    }
    if (lane == 63) wpart[w] = s;
    __syncthreads();
    int wex = 0;
#pragma unroll
    for (int i = 0; i < 3; ++i) if (i < w) wex += wpart[i];
    if (t < NB) bbase[t] = wex + s - v;
    if (t == NB - 1) { bbase[NB] = wex + s; offsets[N] = wex + s; }
}

// One block (256 thr) per bucket: read padded chunk, 512-bin LDS hist + scan
// -> offsets (contiguous), then scatter into compacted csr.
__global__ __launch_bounds__(256) void p3_csr(
    const unsigned* __restrict__ pairs, const int* __restrict__ bcur,
    const int* __restrict__ bbase, int* __restrict__ offsets,
    int* __restrict__ csr, int N)
{
    __shared__ int hist[B2];
    __shared__ int wp[4];
    const int b = blockIdx.x;
    const int p0in = b * CAP, p1in = p0in + bcur[b];
    const int p0out = bbase[b];
    const int dbase = b << B2SHIFT;
    const int lane = threadIdx.x & 63, w = threadIdx.x >> 6;
    hist[threadIdx.x] = 0; hist[threadIdx.x + 256] = 0;
    __syncthreads();
    for (int i = p0in + (int)threadIdx.x; i < p1in; i += 256)
        atomicAdd(&hist[pairs[i] >> SRCBITS], 1);
    __syncthreads();
    const int v0 = hist[2 * threadIdx.x], v1 = hist[2 * threadIdx.x + 1];
    const int t = v0 + v1;
    int s = t;
#pragma unroll
    for (int off = 1; off < 64; off <<= 1) {
        int u = __shfl_up(s, off, 64);
        if (lane >= off) s += u;
    }
    if (lane == 63) wp[w] = s;
    __syncthreads();
    int wex = 0;
#pragma unroll
    for (int i = 0; i < 3; ++i) if (i < w) wex += wp[i];
    const int tex = wex + (s - t);
    const int e0 = tex, e1 = tex + v0;
    const int d0 = dbase + 2 * (int)threadIdx.x, d1 = d0 + 1;
    if (d0 < N) offsets[d0] = p0out + e0;
    if (d1 < N) offsets[d1] = p0out + e1;
    __syncthreads();
    hist[2 * threadIdx.x] = e0; hist[2 * threadIdx.x + 1] = e1;
    __syncthreads();
    for (int i = p0in + (int)threadIdx.x; i < p1in; i += 256) {
        unsigned pk = pairs[i];
        int pos = p0out + atomicAdd(&hist[pk >> SRCBITS], 1);
        csr[pos] = (int)(pk & SRCMASK);
    }
}

// ---------------- GEMM via MFMA (fp32 emulated with bf16 hi/lo split) ----------------
// Output hn is fp16 (normalized rows), nrm holds f32 L2 norms.
__global__ __launch_bounds__(256) void gemm_mfma_k(
    const float* __restrict__ x, const float* __restrict__ W,
    const float* __restrict__ b, unsigned short* __restrict__ hn,
    float* __restrict__ nrm, int n)
{
    __shared__ uint4 sB[2][4][4][64];   // [hi/lo][kc][nt][lane] = 32 KB
    for (int idx = threadIdx.x; idx < 2048; idx += 256) {
        int lanei = idx & 63;
        int f = idx >> 6;
        int nt = f & 3, kc = (f >> 2) & 3, hl = f >> 4;
        int col = nt * 16 + (lanei & 15);
        int kb  = kc * 32 + (lanei >> 4) * 8;
        unsigned u[4];
#pragma unroll
        for (int jj = 0; jj < 4; ++jj) {
            unsigned short h0, l0, h1, l1;
            split_bf16(W[(size_t)(kb + 2 * jj)     * HDIM + col], h0, l0);
            split_bf16(W[(size_t)(kb + 2 * jj + 1) * HDIM + col], h1, l1);
            u[jj] = hl ? ((unsigned)l0 | ((unsigned)l1 << 16))
                       : ((unsigned)h0 | ((unsigned)h1 << 16));
        }
        uint4 q; q.x = u[0]; q.y = u[1]; q.z = u[2]; q.w = u[3];
        sB[hl][kc][nt][lanei] = q;
    }
    __syncthreads();

    const int lane = threadIdx.x & 63;
    const int l15 = lane & 15, l4 = lane >> 4;
    const int gw = (int)((blockIdx.x * 256 + threadIdx.x) >> 6);
    const int nw = (int)((gridDim.x * 256) >> 6);
    const int ntiles = (n + 15) >> 4;

    const float bc0 = b[l15], bc1 = b[16 + l15], bc2 = b[32 + l15], bc3 = b[48 + l15];

    for (int tile = gw; tile < ntiles; tile += nw) {
        const int rowbase = tile << 4;
        int arow = rowbase + l15; if (arow >= n) arow = n - 1;
        const float* xp = x + (size_t)arow * FIN + l4 * 8;

        f32x4 acc0 = {bc0, bc0, bc0, bc0};
        f32x4 acc1 = {bc1, bc1, bc1, bc1};
        f32x4 acc2 = {bc2, bc2, bc2, bc2};
        f32x4 acc3 = {bc3, bc3, bc3, bc3};

#pragma unroll
        for (int kc = 0; kc < 4; ++kc) {
            float4 xa = *(const float4*)(xp + kc * 32);
            float4 xb = *(const float4*)(xp + kc * 32 + 4);
            float v[8] = {xa.x, xa.y, xa.z, xa.w, xb.x, xb.y, xb.z, xb.w};
            short8_t ah, al;
#pragma unroll
            for (int j = 0; j < 8; ++j) {
                unsigned bb = __builtin_bit_cast(unsigned, v[j]);
                ah[j] = (short)(bb >> 16);
                float fl = v[j] - __builtin_bit_cast(float, bb & 0xFFFF0000u);
                al[j] = (short)(__builtin_bit_cast(unsigned, fl) >> 16);
            }
#pragma unroll
            for (int nt = 0; nt < 4; ++nt) {
                short8_t bh = __builtin_bit_cast(short8_t, sB[0][kc][nt][lane]);
                short8_t bl = __builtin_bit_cast(short8_t, sB[1][kc][nt][lane]);
                f32x4* pacc = (nt == 0) ? &acc0 : (nt == 1) ? &acc1 : (nt == 2) ? &acc2 : &acc3;
                *pacc = __builtin_amdgcn_mfma_f32_16x16x32_bf16(ah, bh, *pacc, 0, 0, 0);
                *pacc = __builtin_amdgcn_mfma_f32_16x16x32_bf16(al, bh, *pacc, 0, 0, 0);
                *pacc = __builtin_amdgcn_mfma_f32_16x16x32_bf16(ah, bl, *pacc, 0, 0, 0);
            }
        }

        float ss0 = acc0.x*acc0.x + acc1.x*acc1.x + acc2.x*acc2.x + acc3.x*acc3.x;
        float ss1 = acc0.y*acc0.y + acc1.y*acc1.y + acc2.y*acc2.y + acc3.y*acc3.y;
        float ss2 = acc0.z*acc0.z + acc1.z*acc1.z + acc2.z*acc2.z + acc3.z*acc3.z;
        float ss3 = acc0.w*acc0.w + acc1.w*acc1.w + acc2.w*acc2.w + acc3.w*acc3.w;
#pragma unroll
        for (int m = 1; m < 16; m <<= 1) {
            ss0 += __shfl_xor(ss0, m, 64);
            ss1 += __shfl_xor(ss1, m, 64);
            ss2 += __shfl_xor(ss2, m, 64);
            ss3 += __shfl_xor(ss3, m, 64);
        }
        float n0 = sqrtf(ss0), n1 = sqrtf(ss1), n2 = sqrtf(ss2), n3 = sqrtf(ss3);
        float r0 = 1.0f / fmaxf(n0, 1e-12f), r1 = 1.0f / fmaxf(n1, 1e-12f);
        float r2 = 1.0f / fmaxf(n2, 1e-12f), r3 = 1.0f / fmaxf(n3, 1e-12f);
        const int rowb = rowbase + l4 * 4;
        if (l15 == 0) {
            if (rowb + 0 < n) nrm[rowb + 0] = n0;
            if (rowb + 1 < n) nrm[rowb + 1] = n1;
            if (rowb + 2 < n) nrm[rowb + 2] = n2;
            if (rowb + 3 < n) nrm[rowb + 3] = n3;
        }
#pragma unroll
        for (int nt = 0; nt < 4; ++nt) {
            f32x4 a = (nt == 0) ? acc0 : (nt == 1) ? acc1 : (nt == 2) ? acc2 : acc3;
            const int col = nt * 16 + l15;
            if (rowb + 0 < n) hn[(size_t)(rowb + 0) * HDIM + col] = f2h1(a.x * r0);
            if (rowb + 1 < n) hn[(size_t)(rowb + 1) * HDIM + col] = f2h1(a.y * r1);
            if (rowb + 2 < n) hn[(size_t)(rowb + 2) * HDIM + col] = f2h1(a.z * r2);
            if (rowb + 3 < n) hn[(size_t)(rowb + 3) * HDIM + col] = f2h1(a.w * r3);
        }
    }
}

// ---------------- AGNN propagation: 8-lane subgroup owns one dst, 4-edge unroll ----
__global__ __launch_bounds__(256) void prop_k(
    const unsigned short* __restrict__ hn, const float* __restrict__ nrm,
    const int* __restrict__ offsets, const int* __restrict__ csr,
    const float* __restrict__ beta_ptr,
    unsigned short* __restrict__ hn_out, float* __restrict__ nrm_out,
    float* __restrict__ lsm_out, int n)
{
    const int lane = threadIdx.x & 63;
    const int sl = lane & 7;
    const int wid = (int)((blockIdx.x * 256 + threadIdx.x) >> 6);
    int d = wid * 8 + (lane >> 3);
    const bool dvalid = d < n;
    if (!dvalid) d = n - 1;
    const float beta = beta_ptr ? beta_ptr[0] : 1.0f;
    const float shift = fabsf(beta);

    const uint4 hdu = *(const uint4*)(hn + ((size_t)d << 6) + (sl << 3));
    float hd[8];
    { float2 f0 = h2f2(hdu.x), f1 = h2f2(hdu.y), f2 = h2f2(hdu.z), f3 = h2f2(hdu.w);
      hd[0]=f0.x; hd[1]=f0.y; hd[2]=f1.x; hd[3]=f1.y;
      hd[4]=f2.x; hd[5]=f2.y; hd[6]=f3.x; hd[7]=f3.y; }

    const int i0 = offsets[d], i1 = offsets[d + 1];
    float acc[8] = {0,0,0,0,0,0,0,0};
    float ssum = 0.f;

    int e = i0;
    for (; e + 3 < i1; e += 4) {          // 4 independent gathers in flight
        const int s0 = csr[e], s1 = csr[e + 1], s2 = csr[e + 2], s3 = csr[e + 3];
        const uint4 va = *(const uint4*)(hn + ((size_t)s0 << 6) + (sl << 3));
        const uint4 vb = *(const uint4*)(hn + ((size_t)s1 << 6) + (sl << 3));
        const uint4 vc = *(const uint4*)(hn + ((size_t)s2 << 6) + (sl << 3));
        const uint4 vd = *(const uint4*)(hn + ((size_t)s3 << 6) + (sl << 3));
        const float na = nrm[s0], nb = nrm[s1], nc = nrm[s2], nd = nrm[s3];
        float p0 = dot8(va, hd), p1 = dot8(vb, hd);
        float p2 = dot8(vc, hd), p3 = dot8(vd, hd);
#pragma unroll
        for (int m = 1; m < 8; m <<= 1) {
            p0 += __shfl_xor(p0, m, 64); p1 += __shfl_xor(p1, m, 64);
            p2 += __shfl_xor(p2, m, 64); p3 += __shfl_xor(p3, m, 64);
        }
        const float ev0 = __expf(beta * p0 - shift);
        const float ev1 = __expf(beta * p1 - shift);
        const float ev2 = __expf(beta * p2 - shift);
        const float ev3 = __expf(beta * p3 - shift);
        acc8(ev0 * na, va, acc);
        acc8(ev1 * nb, vb, acc);
        acc8(ev2 * nc, vc, acc);
        acc8(ev3 * nd, vd, acc);
        ssum += (ev0 + ev1) + (ev2 + ev3);
    }
    for (; e < i1; ++e) {
        const int s0 = csr[e];
        const uint4 va = *(const uint4*)(hn + ((size_t)s0 << 6) + (sl << 3));
        const float na = nrm[s0];
        float p0 = dot8(va, hd);
#pragma unroll
        for (int m = 1; m < 8; m <<= 1) p0 += __shfl_xor(p0, m, 64);
        const float ev0 = __expf(beta * p0 - shift);
        acc8(ev0 * na, va, acc);
        ssum += ev0;
    }

    const float rs = 1.0f / ssum;      // self loop => ssum > 0
    float o[8];
#pragma unroll
    for (int j = 0; j < 8; ++j) o[j] = acc[j] * rs;

    if (lsm_out) {
        float mx = o[0];
#pragma unroll
        for (int j = 1; j < 8; ++j) mx = fmaxf(mx, o[j]);
        mx = fmaxf(mx, __shfl_xor(mx, 1, 64));
        mx = fmaxf(mx, __shfl_xor(mx, 2, 64));
        mx = fmaxf(mx, __shfl_xor(mx, 4, 64));
        float es = 0.f;
#pragma unroll
        for (int j = 0; j < 8; ++j) es += __expf(o[j] - mx);
        es += __shfl_xor(es, 1, 64);
        es += __shfl_xor(es, 2, 64);
        es += __shfl_xor(es, 4, 64);
        const float ls = mx + __logf(es);
        if (dvalid) {
            float* op = lsm_out + ((size_t)d << 6) + (sl << 3);
            *(float4*)(op)     = make_float4(o[0]-ls, o[1]-ls, o[2]-ls, o[3]-ls);
            *(float4*)(op + 4) = make_float4(o[4]-ls, o[5]-ls, o[6]-ls, o[7]-ls);
        }
    } else {
        float ss = 0.f;
#pragma unroll
        for (int j = 0; j < 8; ++j) ss = fmaf(o[j], o[j], ss);
        ss += __shfl_xor(ss, 1, 64);
        ss += __shfl_xor(ss, 2, 64);
        ss += __shfl_xor(ss, 4, 64);
        const float norm = sqrtf(ss);
        const float rinv = 1.0f / fmaxf(norm, 1e-12f);
        if (dvalid) {
            uint4 q;
            q.x = f2h2(o[0] * rinv, o[1] * rinv);
            q.y = f2h2(o[2] * rinv, o[3] * rinv);
            q.z = f2h2(o[4] * rinv, o[5] * rinv);
            q.w = f2h2(o[6] * rinv, o[7] * rinv);
            *(uint4*)(hn_out + ((size_t)d << 6) + (sl << 3)) = q;
            if (sl == 0) nrm_out[d] = norm;
        }
    }
}

extern "C" void kernel_launch(void* const* d_in, const int* in_sizes, int n_in,
                              void* d_out, int out_size, void* d_ws, size_t ws_size,
                              hipStream_t stream)
{
    const float* x     = (const float*)d_in[0];
    const int*   ei    = (const int*)d_in[1];   // [2, E] int32
    const float* W1    = (const float*)d_in[2];
    const float* b1    = (const float*)d_in[3];
    const float* beta2 = (const float*)d_in[4];
    float* out = (float*)d_out;

    const int N    = in_sizes[0] / FIN;
    const int E    = in_sizes[1] / 2;
    const int Etot = E + N;
    const int NB   = (N + B2 - 1) >> B2SHIFT;          // 196 buckets
    const int nblk = (Etot + EB - 1) / EB;             // 208 edge blocks

    // ws layout: hn1h[N*64 u16] hn2h[N*64 u16] nrm1[N] nrm2[N]
    //            offsets[N+1] csr[Etot] bcur[256] bbase[257]
    // pairs (u32, NB*CAP = 9.6 MB) ALIASES hn2h (12.8 MB): dead before prop1 writes.
    unsigned short* hn1h = (unsigned short*)d_ws;
    unsigned short* hn2h = hn1h + (size_t)N * HDIM;
    float* nrm1    = (float*)(hn2h + (size_t)N * HDIM);
    float* nrm2    = nrm1 + N;
    int*   offsets = (int*)(nrm2 + N);
    int*   csr     = offsets + (N + 1);
    int*   bcur    = csr + Etot;
    int*   bbase   = bcur + 256;
    unsigned* pairs = (unsigned*)hn2h;

    const dim3 blk(256);

    // ---- CSR build: padded-bucket counting sort, single pass over ei ----
    hipMemsetAsync(bcur, 0, 256 * sizeof(int), stream);
    pc_scatter<<<nblk, blk, 0, stream>>>(ei, bcur, pairs, E, Etot, NB);
    pc_scan<<<1, blk, 0, stream>>>(bcur, bbase, offsets, NB, N);
    p3_csr<<<NB, blk, 0, stream>>>(pairs, bcur, bbase, offsets, csr, N);

    // ---- h = x@W1+b1 (MFMA), normalized, fp16 ----
    const int ntiles = (N + 15) >> 4;
    gemm_mfma_k<<<(ntiles + 3) / 4, blk, 0, stream>>>(x, W1, b1, hn1h, nrm1, N);

    // ---- props: 8 dsts per wave, 32 per block ----
    const int pblocks = (N + 31) / 32;
    prop_k<<<pblocks, blk, 0, stream>>>(hn1h, nrm1, offsets, csr, nullptr,
                                        hn2h, nrm2, nullptr, N);
    prop_k<<<pblocks, blk, 0, stream>>>(hn2h, nrm2, offsets, csr, beta2,
                                        nullptr, nullptr, out, N);
}